// Round 8
// baseline (89.741 us; speedup 1.0000x reference)
//
#include <hip/hip_runtime.h>
#include <cmath>

// Problem constants (match reference)
#define BB 4
#define NN 48
#define PP (NN * NN)   // 2304 (x,y) pairs per plane
#define TT 33
#define RR 16
#define NC 80
#define NI 5
#define NEG (-1000.0f)

// decomposition: block = (b, triple, x-quarter)
#define XS 12          // x-rows per block
#define XP 13          // padded stride for [k][x_local] tiles (gcd(13,32)=1)
#define NTH 192        // 3 waves; 12 x-rows x 16 y-triplets, 3 outs/thread

// ---------------------------------------------------------------------------
// Single standard kernel, ZERO d_ws usage (tests the d_ws-fill dependency
// theory: all prior rounds' pipelines were serialized behind the harness's
// 41 us 256 MiB d_ws poison fill; this kernel has no d_ws dependency).
//
// Block = (b, t, xq): owns output slab out[b, xq*12..+12, :, t].
//   For each of triple t's 5 chains: gather H0T (x-slice, [k][x_local]),
//   H1, H2 (full planes, [k][y]) straight from trans (stride-33 gather;
//   R2 proved parity with coalesced staging — planes are L2-hot, 64 blocks
//   share each b's data); two max-plus products (k-paired -> v_max3_f32);
//   accumulate w_i * exp(S) in registers.  Epilogue: +bias, mask, store.
//
// LDS conflict audit (wave = 4 xl-groups x 16 yt):
//   H0T/S1T reads [k*13+xl]: 16-lane broadcast x 4 addrs stride 13 -> free.
//   H1/H2 reads [k*48+yt*3+j]: 16 addrs stride 3 (distinct mod 32) x 4-way
//     broadcast -> free.  S1T writes [(yt*3+j)*13+xl]: worst 2-way (free).
//   H0T gather writes [k*13+xl], lanes step k -> stride 13 -> free.
// ---------------------------------------------------------------------------
__global__ __launch_bounds__(NTH) void fused_scorer(
    const float* __restrict__ trans,    // [B,N,N,T]
    const int*   __restrict__ rules,    // [Nc,3]
    const float* __restrict__ weights,  // [Nt,Ni] flat
    const float* __restrict__ biases,   // [Nt]
    const int*   __restrict__ mask,     // [B,N,N,R]
    float*       __restrict__ out)      // [B,N,N,R]
{
    __shared__ float H0T[NN * XP];  // [k][x_local] of product 1 (624 f)
    __shared__ float H1 [PP];       // [k][y] of product 1
    __shared__ float H2 [PP];       // [k][y] of product 2
    __shared__ float S1T[NN * XP];  // [k2][x_local] of product 2

    const int blk = blockIdx.x;     // 256 = 4 b x 16 t x 4 xq
    const int xq  = blk & 3;
    const int bt  = blk >> 2;
    const int b   = bt >> 4;
    const int t   = bt & 15;
    const int xbase = xq * XS;

    const int xl = threadIdx.x >> 4;        // 0..11 (x row within quarter)
    const int yt = threadIdx.x & 15;        // 16 y-triplets
    const int y0 = yt * 3;

    const float* tb = trans + (size_t)b * PP * TT;

    float acc_out[3] = {0.0f, 0.0f, 0.0f};  // sum_i w_i*exp(S_i), 3 y's

    for (int ci = 0; ci < NI; ++ci) {
        const int c  = t * NI + ci;
        const int r0 = rules[c * 3 + 0];
        const int r1 = rules[c * 3 + 1];
        const int r2 = rules[c * 3 + 2];
        const float w = weights[c];

        __syncthreads();   // previous chain's product-2 LDS reads complete

        // Gather staging (stride-33; all 3 channels of one (x,k) share the
        // same 132 B span -> L1-friendly; 64 blocks/b -> L2-hot).
        for (int i = threadIdx.x; i < PP; i += NTH) {
            const size_t base = (size_t)i * TT;
            H1[i] = tb[base + r1];
            H2[i] = tb[base + r2];
        }
        for (int i = threadIdx.x; i < XS * NN; i += NTH) {
            const int xls = i / NN;          // 0..11
            const int k   = i - xls * NN;    // 0..47
            H0T[k * XP + xls] = tb[(size_t)((xbase + xls) * NN + k) * TT + r0];
        }
        __syncthreads();

        // ---- product 1: S1[xl, y0..y0+2] ----
        float a0 = -INFINITY, a1 = -INFINITY, a2 = -INFINITY;
        #pragma unroll 4
        for (int kp = 0; kp < NN / 2; ++kp) {
            const int k = kp * 2;
            const float h0 = H0T[k * XP + xl];
            const float h1 = H0T[(k + 1) * XP + xl];
            a0 = fmaxf(a0, fmaxf(h0 + H1[k * NN + y0 + 0], h1 + H1[(k + 1) * NN + y0 + 0]));
            a1 = fmaxf(a1, fmaxf(h0 + H1[k * NN + y0 + 1], h1 + H1[(k + 1) * NN + y0 + 1]));
            a2 = fmaxf(a2, fmaxf(h0 + H1[k * NN + y0 + 2], h1 + H1[(k + 1) * NN + y0 + 2]));
        }
        S1T[(y0 + 0) * XP + xl] = a0;
        S1T[(y0 + 1) * XP + xl] = a1;
        S1T[(y0 + 2) * XP + xl] = a2;
        __syncthreads();

        // ---- product 2: S[xl, y0..y0+2], accumulate w*exp ----
        float s0 = -INFINITY, s1 = -INFINITY, s2 = -INFINITY;
        #pragma unroll 4
        for (int kp = 0; kp < NN / 2; ++kp) {
            const int k = kp * 2;
            const float h0 = S1T[k * XP + xl];
            const float h1 = S1T[(k + 1) * XP + xl];
            s0 = fmaxf(s0, fmaxf(h0 + H2[k * NN + y0 + 0], h1 + H2[(k + 1) * NN + y0 + 0]));
            s1 = fmaxf(s1, fmaxf(h0 + H2[k * NN + y0 + 1], h1 + H2[(k + 1) * NN + y0 + 1]));
            s2 = fmaxf(s2, fmaxf(h0 + H2[k * NN + y0 + 2], h1 + H2[(k + 1) * NN + y0 + 2]));
        }
        acc_out[0] += w * __expf(s0);
        acc_out[1] += w * __expf(s1);
        acc_out[2] += w * __expf(s2);
    }

    // Epilogue: bias + mask-select + direct store of 3 outputs.
    const float bias = biases[t];
    const int xg = xbase + xl;
    #pragma unroll
    for (int j = 0; j < 3; ++j) {
        const size_t oidx = ((size_t)(b * PP + xg * NN + y0 + j)) * RR + t;
        out[oidx] = (mask[oidx] == 0) ? (acc_out[j] + bias) : NEG;
    }
}

extern "C" void kernel_launch(void* const* d_in, const int* in_sizes, int n_in,
                              void* d_out, int out_size, void* d_ws, size_t ws_size,
                              hipStream_t stream)
{
    const float* trans   = (const float*)d_in[0];  // [B,N,N,T] f32
    const int*   mask    = (const int*)  d_in[1];  // [B,N,N,R] i32
    const int*   rules   = (const int*)  d_in[2];  // [Nc,3]    i32
    const float* weights = (const float*)d_in[3];  // [Nt,Ni]   f32
    const float* biases  = (const float*)d_in[4];  // [Nt]      f32
    float* out = (float*)d_out;
    (void)d_ws; (void)ws_size;   // intentionally unused — see kernel comment

    fused_scorer<<<BB * RR * 4, NTH, 0, stream>>>(trans, rules, weights,
                                                  biases, mask, out);
}

// Round 9
// 76.377 us; speedup vs baseline: 1.1750x; 1.1750x over previous
//
#include <hip/hip_runtime.h>
#include <cmath>

// Problem constants (match reference)
#define BB 4
#define NN 48
#define PP (NN * NN)   // 2304 (x,y) pairs per plane
#define NP 49          // padded row stride for transposed LDS tiles
#define TT 33
#define RR 16
#define NC 80
#define NI 5
#define NEG (-1000.0f)

// ---------------------------------------------------------------------------
// R4 configuration — best measured (75.23 us). Three dispatches:
//   transpose (1.5 us) + chain_dp (~27 us) + combine (~3 us), after the
//   harness's fixed 41.5 us d_ws poison fill.
// ---------------------------------------------------------------------------

__global__ __launch_bounds__(256) void transpose_kernel(
    const float* __restrict__ trans,   // [B, 2304, 33]
    float*       __restrict__ tpose)   // [B, 33, 2304]
{
    __shared__ float tile[64 * TT];    // 64 p x 33 t
    const int blk = blockIdx.x;        // B * 36
    const int b   = blk / 36;
    const int p0  = (blk - b * 36) * 64;

    const float4* src = (const float4*)(trans + ((size_t)b * PP + p0) * TT);
    for (int j = threadIdx.x; j < 64 * TT / 4; j += 256)
        ((float4*)tile)[j] = src[j];
    __syncthreads();

    for (int j = threadIdx.x; j < TT * 64; j += 256) {
        const int t  = j >> 6;
        const int pl = j & 63;
        tpose[((size_t)b * TT + t) * PP + p0 + pl] = tile[pl * TT + t];
    }
}

__global__ __launch_bounds__(192) void chain_dp_kernel(
    const float* __restrict__ tpose,    // [B, 33, 2304]
    const int*   __restrict__ rules,    // [Nc,3]
    const float* __restrict__ weights,  // [Nc]
    float*       __restrict__ sw)       // [B,Nc,N,N]
{
    __shared__ float H0T[NN * NP];  // A of product 1, transposed [k][x]
    __shared__ float H1 [PP];       // B of product 1, [k][y]
    __shared__ float H2 [PP];       // B of product 2, [k][y]
    __shared__ float S1T[NN * NP];  // A of product 2, transposed [k][x]

    const int bc = blockIdx.x;
    const int b  = bc / NC;
    const int c  = bc - b * NC;

    const int r0 = rules[c * 3 + 0];
    const int r1 = rules[c * 3 + 1];
    const int r2 = rules[c * 3 + 2];

    const float* p0 = tpose + ((size_t)b * TT + r0) * PP;
    const float* p1 = tpose + ((size_t)b * TT + r1) * PP;
    const float* p2 = tpose + ((size_t)b * TT + r2) * PP;

    for (int j = threadIdx.x; j < PP / 4; j += 192) {
        ((float4*)H1)[j] = ((const float4*)p1)[j];
        ((float4*)H2)[j] = ((const float4*)p2)[j];
        const float4 v0 = ((const float4*)p0)[j];
        const int x = (4 * j) / NN;
        const int k = (4 * j) - x * NN;   // 48 % 4 == 0: all 4 in one row
        H0T[(k + 0) * NP + x] = v0.x;
        H0T[(k + 1) * NP + x] = v0.y;
        H0T[(k + 2) * NP + x] = v0.z;
        H0T[(k + 3) * NP + x] = v0.w;
    }
    __syncthreads();

    const int tx = threadIdx.x & 15;   // 16 x-tiles (3 wide)
    const int ty = threadIdx.x >> 4;   // 12 y-tiles (4 wide)
    const int x0 = tx * 3;
    const int y0 = ty * 4;

    // ---- product 1: S1 = H0 (x) H1 ----
    float acc[3][4];
    #pragma unroll
    for (int jx = 0; jx < 3; ++jx)
        #pragma unroll
        for (int jy = 0; jy < 4; ++jy) acc[jx][jy] = -INFINITY;

    #pragma unroll 4
    for (int kp = 0; kp < NN / 2; ++kp) {
        const int k = kp * 2;
        float a0[3], a1[3];
        #pragma unroll
        for (int jx = 0; jx < 3; ++jx) {
            a0[jx] = H0T[k * NP + x0 + jx];
            a1[jx] = H0T[(k + 1) * NP + x0 + jx];
        }
        const float4 bv0 = *(const float4*)&H1[k * NN + y0];
        const float4 bv1 = *(const float4*)&H1[(k + 1) * NN + y0];
        const float b0[4] = {bv0.x, bv0.y, bv0.z, bv0.w};
        const float b1[4] = {bv1.x, bv1.y, bv1.z, bv1.w};
        #pragma unroll
        for (int jx = 0; jx < 3; ++jx)
            #pragma unroll
            for (int jy = 0; jy < 4; ++jy)
                acc[jx][jy] = fmaxf(acc[jx][jy],
                                    fmaxf(a0[jx] + b0[jy], a1[jx] + b1[jy]));
    }

    #pragma unroll
    for (int jx = 0; jx < 3; ++jx)
        #pragma unroll
        for (int jy = 0; jy < 4; ++jy)
            S1T[(y0 + jy) * NP + x0 + jx] = acc[jx][jy];
    __syncthreads();

    // ---- product 2: S = S1 (x) H2, fused exp*weight epilogue ----
    float acc2[3][4];
    #pragma unroll
    for (int jx = 0; jx < 3; ++jx)
        #pragma unroll
        for (int jy = 0; jy < 4; ++jy) acc2[jx][jy] = -INFINITY;

    #pragma unroll 4
    for (int kp = 0; kp < NN / 2; ++kp) {
        const int k = kp * 2;
        float a0[3], a1[3];
        #pragma unroll
        for (int jx = 0; jx < 3; ++jx) {
            a0[jx] = S1T[k * NP + x0 + jx];
            a1[jx] = S1T[(k + 1) * NP + x0 + jx];
        }
        const float4 bv0 = *(const float4*)&H2[k * NN + y0];
        const float4 bv1 = *(const float4*)&H2[(k + 1) * NN + y0];
        const float b0[4] = {bv0.x, bv0.y, bv0.z, bv0.w};
        const float b1[4] = {bv1.x, bv1.y, bv1.z, bv1.w};
        #pragma unroll
        for (int jx = 0; jx < 3; ++jx)
            #pragma unroll
            for (int jy = 0; jy < 4; ++jy)
                acc2[jx][jy] = fmaxf(acc2[jx][jy],
                                     fmaxf(a0[jx] + b0[jy], a1[jx] + b1[jy]));
    }

    const float wgt = weights[c];
    float* outp = sw + (size_t)bc * PP;
    #pragma unroll
    for (int jx = 0; jx < 3; ++jx) {
        float4 o;
        o.x = __expf(acc2[jx][0]) * wgt;
        o.y = __expf(acc2[jx][1]) * wgt;
        o.z = __expf(acc2[jx][2]) * wgt;
        o.w = __expf(acc2[jx][3]) * wgt;
        *(float4*)&outp[(x0 + jx) * NN + y0] = o;
    }
}

__global__ __launch_bounds__(256) void combine_kernel(
    const float* __restrict__ sw,      // [B,Nc,N,N]
    const int*   __restrict__ mask,    // [B,N,N,R]
    const float* __restrict__ biases,  // [R]
    float*       __restrict__ out)     // [B,N,N,R]
{
    const int tq = threadIdx.x >> 7;                       // t-half 0/1
    const int pl = blockIdx.x * 128 + (threadIdx.x & 127); // (b,p) linear
    if (pl >= BB * PP) return;
    const int b = pl / PP;
    const int p = pl - b * PP;

    const float* base = sw + (size_t)b * NC * PP + p;

    float acc[8];
    #pragma unroll
    for (int tt = 0; tt < 8; ++tt) {
        const int t = tq * 8 + tt;
        float s = biases[t];
        #pragma unroll
        for (int i = 0; i < NI; ++i)
            s += base[(size_t)(t * NI + i) * PP];
        acc[tt] = s;
    }

    const int4* m4 = (const int4*)(mask + (size_t)pl * RR + tq * 8);
    float4*     o4 = (float4*)(out + (size_t)pl * RR + tq * 8);
    #pragma unroll
    for (int q = 0; q < 2; ++q) {
        const int4 m = m4[q];
        float4 o;
        o.x = (m.x == 0) ? acc[q * 4 + 0] : NEG;
        o.y = (m.y == 0) ? acc[q * 4 + 1] : NEG;
        o.z = (m.z == 0) ? acc[q * 4 + 2] : NEG;
        o.w = (m.w == 0) ? acc[q * 4 + 3] : NEG;
        o4[q] = o;
    }
}

extern "C" void kernel_launch(void* const* d_in, const int* in_sizes, int n_in,
                              void* d_out, int out_size, void* d_ws, size_t ws_size,
                              hipStream_t stream)
{
    const float* trans   = (const float*)d_in[0];  // [B,N,N,T] f32
    const int*   mask    = (const int*)  d_in[1];  // [B,N,N,R] i32
    const int*   rules   = (const int*)  d_in[2];  // [Nc,3]    i32
    const float* weights = (const float*)d_in[3];  // [Nt,Ni]   f32
    const float* biases  = (const float*)d_in[4];  // [Nt]      f32
    float* out = (float*)d_out;

    float* tpose = (float*)d_ws;                   // [B,33,2304] = 1.22 MB
    float* sw    = tpose + (size_t)BB * TT * PP;   // [B,Nc,48,48] = 2.95 MB

    transpose_kernel<<<BB * 36, 256, 0, stream>>>(trans, tpose);

    chain_dp_kernel<<<BB * NC, 192, 0, stream>>>(tpose, rules, weights, sw);

    const int total2 = BB * PP * 2;                // 2 threads per (b,p)
    combine_kernel<<<(total2 + 255) / 256, 256, 0, stream>>>(sw, mask, biases, out);
}